// Round 5
// baseline (181.069 us; speedup 1.0000x reference)
//
#include <hip/hip_runtime.h>
#include <math.h>

typedef float v2 __attribute__((ext_vector_type(2)));

// B=128, IN=256, H=1024 -> 128 steps of (layerA, layerB). nA=512, nB=511.
#define NBATCH 128
#define NIN    256
#define NH     1024
#define NSTEPS 128
#define NB     511

// Angle table: [layer][j(0..3)][g(0..255)] float4 {c0,s0,c1,s1}
//   g = global lane (4 waves x 64 lanes), owns channels 4g..4g+3
//   j=0: A pair 2g     (ch 4g,4g+1)
//   j=1: A pair 2g+1   (ch 4g+2,4g+3)
//   j=2: B pair 2g     (ch 4g+1,4g+2)   always valid (2g <= 510)
//   j=3: B pair 2g+1   (ch 4g+3,4g+4)   g=255 -> pair 511 -> identity
// Left-boundary angle for lane g is entry (j=3, g-1). Table = 2 MB; ih = 1 MB.
#define TAB_F4_PER_L 1024
#define IH_OFF (NSTEPS * TAB_F4_PER_L * 4)   // float offset; ih float4 = {R,I,R,I}

#define GEMM_BLOCKS 256
#define TRIG_BLOCKS 512                      // 512*256 = 128*1024 exactly

static __device__ __forceinline__ v2 to2(float a, float b) { v2 r; r.x = a; r.y = b; return r; }

// ---------------------------------------------------------------------------
// prep: blocks [0,256) complex gemm ih = in @ W^T + bias; [256,768) trig table
// ---------------------------------------------------------------------------
__global__ __launch_bounds__(256) void prep_kernel(
    const float* __restrict__ inR, const float* __restrict__ inI,
    const float* __restrict__ wR,  const float* __restrict__ wI,
    const float* __restrict__ biasR, const float* __restrict__ biasI,
    const float* __restrict__ A0, const float* __restrict__ A1,
    const float* __restrict__ B0, const float* __restrict__ B1,
    float* __restrict__ ws)
{
    __shared__ v2 xs[256][17];   // [k][b]  {xr,xi}
    __shared__ v2 wsh[32][34];   // [k][h]  {wr,wi}; stride 34 v2 = 272 B (16-aligned rows)

    if (blockIdx.x >= GEMM_BLOCKS) {
        // ---------------- trig branch ----------------
        int idx = (blockIdx.x - GEMM_BLOCKS) * 256 + threadIdx.x;
        int l = idx >> 10;
        int s = idx & 1023;
        int j = s >> 8, g = s & 255;
        float a0, a1;
        bool ident = false;
        if (j < 2) {
            int p = 2 * g + j;                    // A pair, always < 512
            a0 = A0[l * 512 + p]; a1 = A1[l * 512 + p];
        } else {
            int p = 2 * g + (j - 2);              // B pair
            if (p < NB) { a0 = B0[l * NB + p]; a1 = B1[l * NB + p]; }
            else ident = true;
        }
        float4 v;
        if (ident) v = make_float4(1.f, 0.f, 1.f, 0.f);
        else {
            float s0, c0, s1, c1;
            __sincosf(a0, &s0, &c0);
            __sincosf(a1, &s1, &c1);
            v = make_float4(c0, s0, c1, s1);
        }
        ((float4*)ws)[l * TAB_F4_PER_L + j * 256 + g] = v;
        return;
    }

    // ---------------- gemm branch: 32h x 16b tile ----------------
    const int ht = blockIdx.x >> 3, bt = blockIdx.x & 7;
    const int h0 = ht * 32, b0 = bt * 16;
    const int tid = threadIdx.x;

    // stage inputs for 16 batch rows: xs[k][b] = {inR, inI}
    {
        int b = tid >> 4, k4 = tid & 15;
#pragma unroll
        for (int p = 0; p < 4; ++p) {
            int k0 = p * 64 + k4 * 4;
            float4 vr = *(const float4*)(inR + (b0 + b) * NIN + k0);
            float4 vi = *(const float4*)(inI + (b0 + b) * NIN + k0);
            xs[k0 + 0][b] = to2(vr.x, vi.x);
            xs[k0 + 1][b] = to2(vr.y, vi.y);
            xs[k0 + 2][b] = to2(vr.z, vi.z);
            xs[k0 + 3][b] = to2(vr.w, vi.w);
        }
    }

    const int hg = tid & 15, bl = tid >> 4;   // thread: 2 h (h0+2hg, +1), 1 b
    v2 acc0 = to2(0.f, 0.f), acc1 = to2(0.f, 0.f);

    for (int c = 0; c < 8; ++c) {
        __syncthreads();
        // stage weight chunk: 32 h x 32 k as {wr,wi}
        {
            int hh = tid >> 3, k4 = tid & 7;
            float4 vr = *(const float4*)(wR + (h0 + hh) * NIN + c * 32 + k4 * 4);
            float4 vi = *(const float4*)(wI + (h0 + hh) * NIN + c * 32 + k4 * 4);
            wsh[k4 * 4 + 0][hh] = to2(vr.x, vi.x);
            wsh[k4 * 4 + 1][hh] = to2(vr.y, vi.y);
            wsh[k4 * 4 + 2][hh] = to2(vr.z, vi.z);
            wsh[k4 * 4 + 3][hh] = to2(vr.w, vi.w);
        }
        __syncthreads();
#pragma unroll
        for (int k = 0; k < 32; ++k) {
            float4 wv = *(const float4*)&wsh[k][hg * 2];   // {wr0,wi0,wr1,wi1}
            v2 w0 = to2(wv.x, wv.y), w1 = to2(wv.z, wv.w);
            v2 xv = xs[c * 32 + k][bl];
            acc0 += to2(xv.x, xv.x) * w0 + to2(xv.y, xv.y) * to2(-w0.y, w0.x);
            acc1 += to2(xv.x, xv.x) * w1 + to2(xv.y, xv.y) * to2(-w1.y, w1.x);
        }
    }
    int h = h0 + hg * 2, b = b0 + bl;
    acc0 += to2(biasR[h], biasI[h]);
    acc1 += to2(biasR[h + 1], biasI[h + 1]);
    ((float4*)(ws + IH_OFF))[b * 512 + (h >> 1)] =
        make_float4(acc0.x, acc0.y, acc1.x, acc1.y);
}

// ---------------------------------------------------------------------------
// mesh: 4 waves per batch row, 4 channels/lane. Round-4 sync structure,
// but the angle table is now staged through LDS with a tri-buffered
// global_load_lds pipeline: per step, lanes ds_read T (conflict-free 16B/lane,
// ~64cy) instead of global loads (~200-400cy). Stage of layer l+2 is issued
// right after the step-l barrier; vmcnt(0) just before each barrier proves
// the next layer's buffer is resident. Next-layer T is prefetched into
// registers post-barrier so the step-top ds_read latency is off the path.
// ---------------------------------------------------------------------------
__device__ __forceinline__ void mzi(const float4 t, v2& a, v2& b)
{
    // p = e^{i t0} a ; a' = c1 p + i s1 b ; b' = i s1 p + c1 b
    v2 P  = to2(t.x, t.y) * to2(a.x, a.x) + to2(-t.y, t.x) * to2(a.y, a.y);
    v2 na = to2(t.z, t.z) * P + to2(-t.w, t.w) * to2(b.y, b.x);
    b     = to2(t.z, t.z) * b + to2(-t.w, t.w) * to2(P.y, P.x);
    a = na;
}

// stage one 16 KB layer: each wave issues 4 x global_load_lds dwordx4 (1 KB each)
__device__ __forceinline__ void stage_layer(const float4* __restrict__ tab, int l,
                                            float4* dst, int w, int lane)
{
    const float4* src = tab + l * TAB_F4_PER_L + w * 256 + lane;  // per-lane
    float4* d = dst + w * 256;                                    // wave-uniform
#pragma unroll
    for (int c = 0; c < 4; ++c) {
        __builtin_amdgcn_global_load_lds(
            (const __attribute__((address_space(1))) unsigned int*)(src + c * 64),
            (__attribute__((address_space(3))) unsigned int*)(d + c * 64),
            16, 0, 0);
    }
}

__global__ __launch_bounds__(256, 1) void mesh_kernel(
    const float* __restrict__ stateR, const float* __restrict__ stateI,
    const float* __restrict__ omega,  const float* __restrict__ mod_bias,
    const float* __restrict__ ws, float* __restrict__ out)
{
    const int b = blockIdx.x;
    const int g = threadIdx.x;         // global lane 0..255, channels 4g..4g+3
    const int lane = g & 63;
    const int w = g >> 6;
    const float4* tab = (const float4*)ws;

    __shared__ float4 tb[3][TAB_F4_PER_L];   // 48 KB tri-buffer
    __shared__ v2 sx0[2][3];
    __shared__ v2 sx3[2][3];

    v2 x[4];
    {
        float4 r = *(const float4*)(stateR + b * NH + 4 * g);
        float4 i = *(const float4*)(stateI + b * NH + 4 * g);
        x[0] = to2(r.x, i.x);
        x[1] = to2(r.y, i.y);
        x[2] = to2(r.z, i.z);
        x[3] = to2(r.w, i.w);
    }

    // prologue: stage layers 0 and 1, drain, full barrier once
    stage_layer(tab, 0, &tb[0][0], w, lane);
    stage_layer(tab, 1, &tb[1][0], w, lane);
    __asm__ volatile("s_waitcnt vmcnt(0)" ::: "memory");
    __syncthreads();

    // T registers for layer 0
    float4 T0 = tb[0][g], T1 = tb[0][256 + g], T2 = tb[0][512 + g], T3 = tb[0][768 + g];
    float4 TL = tb[0][768 + ((g - 1) & 255)];
    if (g == 0) TL = make_float4(1.f, 0.f, 1.f, 0.f);

    int s = 0;
    for (int l = 0; l < NSTEPS; ++l) {
        const int par = l & 1;
        // A layer: both pairs lane-local
        mzi(T0, x[0], x[1]);
        mzi(T1, x[2], x[3]);
        // edge lanes publish post-A boundary values
        if (lane == 0 && w > 0)  sx0[par][w - 1] = x[0];
        if (lane == 63 && w < 3) sx3[par][w] = x[3];
        // lgkm: publish writes visible; vmcnt: stage(l+1) resident (issued ~1 step ago)
        __asm__ volatile("s_waitcnt vmcnt(0) lgkmcnt(0)" ::: "memory");
        __builtin_amdgcn_s_barrier();
        __asm__ volatile("" ::: "memory");

        // stage layer l+2 into the buffer freed by layer l-1
        int s2 = s + 2; if (s2 >= 3) s2 -= 3;
        if (l + 2 < NSTEPS) stage_layer(tab, l + 2, &tb[s2][0], w, lane);

        // intra-wave boundary values via shuffle
        float rcr = __shfl_down(x[0].x, 1, 64);
        float rci = __shfl_down(x[0].y, 1, 64);
        float lcr = __shfl_up(x[3].x, 1, 64);
        float lci = __shfl_up(x[3].y, 1, 64);
        // edge lanes read neighbor values from LDS
        if (lane == 63 && w < 3) { v2 t = sx0[par][w]; rcr = t.x; rci = t.y; }
        if (lane == 0 && w > 0)  { v2 t = sx3[par][w - 1]; lcr = t.x; lci = t.y; }

        // B local pair -- independent of boundary data; covers lgkm latency
        mzi(T2, x[1], x[2]);

        // prefetch next layer's T registers (buffer s1 resident per pre-barrier vmcnt)
        int s1 = s + 1; if (s1 >= 3) s1 -= 3;
        float4 N0, N1, N2, N3, NL;
        if (l + 1 < NSTEPS) {
            N0 = tb[s1][g];
            N1 = tb[s1][256 + g];
            N2 = tb[s1][512 + g];
            N3 = tb[s1][768 + g];
            NL = tb[s1][768 + ((g - 1) & 255)];
        } else {
            N0 = N1 = N2 = N3 = NL = make_float4(1.f, 0.f, 1.f, 0.f);
        }

        // right boundary: a-side update of x[3] with right neighbor's post-A x0
        {
            v2 P = to2(T3.x, T3.y) * to2(x[3].x, x[3].x) + to2(-T3.y, T3.x) * to2(x[3].y, x[3].y);
            x[3] = to2(T3.z, T3.z) * P + to2(-T3.w, T3.w) * to2(rci, rcr);
        }
        // left boundary: b-side update of x[0] with left neighbor's post-A x3
        {
            v2 P = to2(TL.x, TL.y) * to2(lcr, lcr) + to2(-TL.y, TL.x) * to2(lci, lci);
            x[0] = to2(TL.z, TL.z) * x[0] + to2(-TL.w, TL.w) * to2(P.y, P.x);
        }

        T0 = N0; T1 = N1; T2 = N2; T3 = N3; TL = NL;
        if (g == 0) TL = make_float4(1.f, 0.f, 1.f, 0.f);
        s = s1;
    }

    // epilogue: phase, + ih, modReLU  (channels 4g..4g+3)
    float4 o4 = *(const float4*)(omega + 4 * g);
    float4 m4 = *(const float4*)(mod_bias + 4 * g);
    const float4* ihp = (const float4*)(ws + IH_OFF) + b * 512 + 2 * g;
    float4 ih0 = ihp[0], ih1 = ihp[1];   // {R,I,R,I} ch 4g,4g+1 / 4g+2,4g+3

    float om[4] = { o4.x, o4.y, o4.z, o4.w };
    float mb[4] = { m4.x, m4.y, m4.z, m4.w };
    float ihr[4] = { ih0.x, ih0.z, ih1.x, ih1.z };
    float ihi[4] = { ih0.y, ih0.w, ih1.y, ih1.w };
    float oR[4], oI[4];
#pragma unroll
    for (int j = 0; j < 4; ++j) {
        float so, co;
        __sincosf(om[j], &so, &co);
        float zr = ihr[j] + co * x[j].x - so * x[j].y;
        float zi = ihi[j] + so * x[j].x + co * x[j].y;
        float mag = sqrtf(zr * zr + zi * zi);
        float sc = fmaxf(mag + mb[j], 0.f) / fmaxf(mag, 1e-8f);
        oR[j] = sc * zr;
        oI[j] = sc * zi;
    }
    *(float4*)(out + b * NH + 4 * g) = make_float4(oR[0], oR[1], oR[2], oR[3]);
    *(float4*)(out + NBATCH * NH + b * NH + 4 * g) = make_float4(oI[0], oI[1], oI[2], oI[3]);
}

// ---------------------------------------------------------------------------
extern "C" void kernel_launch(void* const* d_in, const int* in_sizes, int n_in,
                              void* d_out, int out_size, void* d_ws, size_t ws_size,
                              hipStream_t stream)
{
    const float* inputsR = (const float*)d_in[0];
    const float* inputsI = (const float*)d_in[1];
    const float* stateR  = (const float*)d_in[2];
    const float* stateI  = (const float*)d_in[3];
    const float* weightR = (const float*)d_in[4];
    const float* weightI = (const float*)d_in[5];
    const float* biasR   = (const float*)d_in[6];
    const float* biasI   = (const float*)d_in[7];
    const float* angleA0 = (const float*)d_in[8];
    const float* angleA1 = (const float*)d_in[9];
    const float* angleB0 = (const float*)d_in[10];
    const float* angleB1 = (const float*)d_in[11];
    const float* omega   = (const float*)d_in[12];
    const float* mod_b   = (const float*)d_in[13];
    float* ws = (float*)d_ws;
    float* out = (float*)d_out;

    hipLaunchKernelGGL(prep_kernel, dim3(GEMM_BLOCKS + TRIG_BLOCKS), dim3(256),
                       0, stream, inputsR, inputsI, weightR, weightI,
                       biasR, biasI, angleA0, angleA1, angleB0, angleB1, ws);
    hipLaunchKernelGGL(mesh_kernel, dim3(NBATCH), dim3(256), 0, stream,
                       stateR, stateI, omega, mod_b, ws, out);
}

// Round 6
// 157.947 us; speedup vs baseline: 1.1464x; 1.1464x over previous
//
#include <hip/hip_runtime.h>
#include <math.h>

typedef float v2 __attribute__((ext_vector_type(2)));

// B=128, IN=256, H=1024 -> 128 steps of (layerA, layerB). nA=512, nB=511.
#define NBATCH 128
#define NIN    256
#define NH     1024
#define NSTEPS 128
#define NB     511
#define CHUNK  32          // steps between halo exchanges (halo 64 ch/side, spread 2/step)

// Angle table, per layer (stride 1160 float4):
//   A entries: idx = 32 + p,  p in [-32, 544): real for p in [0,512), else identity
//   B entries: idx = 609 + p, p in [-33, 551): real for p in [0,511), else identity
// Ghost (identity) entries make wave-edge/mesh-edge MZIs exact pass-throughs.
// Table = 128*1160*16 B = 2.38 MB; ih = 1 MB.
#define TAB_STRIDE 1160
#define IH_OFF (NSTEPS * TAB_STRIDE * 4)     // float offset; ih float4 = {R,I,R,I}

#define GEMM_BLOCKS 256
#define TRIG_BLOCKS 580                      // 580*256 = 128*1160 exactly

static __device__ __forceinline__ v2 to2(float a, float b) { v2 r; r.x = a; r.y = b; return r; }

// ---------------------------------------------------------------------------
// prep: blocks [0,256) complex gemm ih = in @ W^T + bias; rest: trig table
// ---------------------------------------------------------------------------
__global__ __launch_bounds__(256) void prep_kernel(
    const float* __restrict__ inR, const float* __restrict__ inI,
    const float* __restrict__ wR,  const float* __restrict__ wI,
    const float* __restrict__ biasR, const float* __restrict__ biasI,
    const float* __restrict__ A0, const float* __restrict__ A1,
    const float* __restrict__ B0, const float* __restrict__ B1,
    float* __restrict__ ws)
{
    __shared__ v2 xs[256][17];   // [k][b]  {xr,xi}
    __shared__ v2 wsh[32][34];   // [k][h]  {wr,wi}

    if (blockIdx.x >= GEMM_BLOCKS) {
        // ---------------- trig branch ----------------
        int idx = (blockIdx.x - GEMM_BLOCKS) * 256 + threadIdx.x;  // 0..148479
        int l = idx / TAB_STRIDE;
        int i = idx - l * TAB_STRIDE;
        float a0 = 0.f, a1 = 0.f;
        bool ident;
        if (i < 576) {
            int p = i - 32;                       // A pair
            ident = (p < 0 || p >= 512);
            if (!ident) { a0 = A0[l * 512 + p]; a1 = A1[l * 512 + p]; }
        } else {
            int p = i - 609;                      // B pair
            ident = (p < 0 || p >= NB);
            if (!ident) { a0 = B0[l * NB + p]; a1 = B1[l * NB + p]; }
        }
        float4 v;
        if (ident) v = make_float4(1.f, 0.f, 1.f, 0.f);
        else {
            float s0, c0, s1, c1;
            __sincosf(a0, &s0, &c0);
            __sincosf(a1, &s1, &c1);
            v = make_float4(c0, s0, c1, s1);
        }
        ((float4*)ws)[l * TAB_STRIDE + i] = v;
        return;
    }

    // ---------------- gemm branch: 32h x 16b tile ----------------
    const int ht = blockIdx.x >> 3, bt = blockIdx.x & 7;
    const int h0 = ht * 32, b0 = bt * 16;
    const int tid = threadIdx.x;

    {
        int b = tid >> 4, k4 = tid & 15;
#pragma unroll
        for (int p = 0; p < 4; ++p) {
            int k0 = p * 64 + k4 * 4;
            float4 vr = *(const float4*)(inR + (b0 + b) * NIN + k0);
            float4 vi = *(const float4*)(inI + (b0 + b) * NIN + k0);
            xs[k0 + 0][b] = to2(vr.x, vi.x);
            xs[k0 + 1][b] = to2(vr.y, vi.y);
            xs[k0 + 2][b] = to2(vr.z, vi.z);
            xs[k0 + 3][b] = to2(vr.w, vi.w);
        }
    }

    const int hg = tid & 15, bl = tid >> 4;
    v2 acc0 = to2(0.f, 0.f), acc1 = to2(0.f, 0.f);

    for (int c = 0; c < 8; ++c) {
        __syncthreads();
        {
            int hh = tid >> 3, k4 = tid & 7;
            float4 vr = *(const float4*)(wR + (h0 + hh) * NIN + c * 32 + k4 * 4);
            float4 vi = *(const float4*)(wI + (h0 + hh) * NIN + c * 32 + k4 * 4);
            wsh[k4 * 4 + 0][hh] = to2(vr.x, vi.x);
            wsh[k4 * 4 + 1][hh] = to2(vr.y, vi.y);
            wsh[k4 * 4 + 2][hh] = to2(vr.z, vi.z);
            wsh[k4 * 4 + 3][hh] = to2(vr.w, vi.w);
        }
        __syncthreads();
#pragma unroll
        for (int k = 0; k < 32; ++k) {
            float4 wv = *(const float4*)&wsh[k][hg * 2];
            v2 w0 = to2(wv.x, wv.y), w1 = to2(wv.z, wv.w);
            v2 xv = xs[c * 32 + k][bl];
            acc0 += to2(xv.x, xv.x) * w0 + to2(xv.y, xv.y) * to2(-w0.y, w0.x);
            acc1 += to2(xv.x, xv.x) * w1 + to2(xv.y, xv.y) * to2(-w1.y, w1.x);
        }
    }
    int h = h0 + hg * 2, b = b0 + bl;
    acc0 += to2(biasR[h], biasI[h]);
    acc1 += to2(biasR[h + 1], biasI[h + 1]);
    ((float4*)(ws + IH_OFF))[b * 512 + (h >> 1)] =
        make_float4(acc0.x, acc0.y, acc1.x, acc1.y);
}

// ---------------------------------------------------------------------------
// mesh: 4 waves per batch row. Each wave: 256 owned channels + 64-ch halo
// each side = 384 ch = 6 ch/lane. Dependency spreads <=2 ch/side/step, so
// 32 steps run with ZERO inter-wave sync (cross-lane B-pairs are intra-wave
// shuffles -- lockstep, no barrier). Every 32 steps: owned channels ->
// canonical LDS, barrier, full re-read (halo refresh), barrier. 6 barriers
// total. Ghost channels (outside [0,1024)) stay finite (zero-init) and hit
// identity angle entries -> exact pass-through, no NaN propagation.
// T-table genuinely double-buffered: 7 float4/step = 56 VGPR for 2 buffers.
// ---------------------------------------------------------------------------
__device__ __forceinline__ void mzi(const float4 t, v2& a, v2& b)
{
    // p = e^{i t0} a ; a' = c1 p + i s1 b ; b' = i s1 p + c1 b
    v2 P  = to2(t.x, t.y) * to2(a.x, a.x) + to2(-t.y, t.x) * to2(a.y, a.y);
    v2 na = to2(t.z, t.z) * P + to2(-t.w, t.w) * to2(b.y, b.x);
    b     = to2(t.z, t.z) * b + to2(-t.w, t.w) * to2(P.y, P.x);
    a = na;
}

// lane channels: cb..cb+5 (cb even). A pairs pa,pa+1,pa+2 (pa=cb/2).
// B local pairs pa,pa+1; right boundary pair pa+2 (x5 a-side, partner = next
// lane's post-A x0); left boundary pair pa-1 (x0 b-side, partner = prev
// lane's post-A x5). Wave-edge shuffles return own value (finite) and the
// corresponding angles are halo/ghost -> decay stays within halo budget.
__device__ __forceinline__ void stepf(v2 x[6], const float4 T[7])
{
    mzi(T[0], x[0], x[1]);
    mzi(T[1], x[2], x[3]);
    mzi(T[2], x[4], x[5]);
    float rcr = __shfl_down(x[0].x, 1, 64);
    float rci = __shfl_down(x[0].y, 1, 64);
    float lcr = __shfl_up(x[5].x, 1, 64);
    float lci = __shfl_up(x[5].y, 1, 64);
    mzi(T[4], x[1], x[2]);
    mzi(T[5], x[3], x[4]);
    // right boundary: a-side update of x[5]
    {
        const float4 t = T[6];
        v2 P = to2(t.x, t.y) * to2(x[5].x, x[5].x) + to2(-t.y, t.x) * to2(x[5].y, x[5].y);
        x[5] = to2(t.z, t.z) * P + to2(-t.w, t.w) * to2(rci, rcr);
    }
    // left boundary: b-side update of x[0]
    {
        const float4 t = T[3];
        v2 P = to2(t.x, t.y) * to2(lcr, lcr) + to2(-t.y, t.x) * to2(lci, lci);
        x[0] = to2(t.z, t.z) * x[0] + to2(-t.w, t.w) * to2(P.y, P.x);
    }
}

#define LOADT(T, l)                                                        \
    do {                                                                   \
        const float4* _a = tab + (l) * TAB_STRIDE + 32 + pa;               \
        T[0] = _a[0]; T[1] = _a[1]; T[2] = _a[2];                          \
        const float4* _b = tab + (l) * TAB_STRIDE + 609 + pa;              \
        T[3] = _b[-1]; T[4] = _b[0]; T[5] = _b[1]; T[6] = _b[2];           \
    } while (0)

__global__ __launch_bounds__(256, 1) void mesh_kernel(
    const float* __restrict__ stateR, const float* __restrict__ stateI,
    const float* __restrict__ omega,  const float* __restrict__ mod_bias,
    const float* __restrict__ ws, float* __restrict__ out)
{
    const int b = blockIdx.x;
    const int g = threadIdx.x;
    const int lane = g & 63;
    const int w = g >> 6;
    const int wb = w * 256;                 // wave's owned range [wb, wb+256)
    const int cb = wb - 64 + 6 * lane;      // lane's channel base (even)
    const int pa = cb / 2;
    const float4* tab = (const float4*)ws;

    __shared__ v2 can[NH];                  // canonical state, 8 KB

    // stage initial state into canonical (coalesced), then gather per-lane
    {
        float4 r = ((const float4*)(stateR + b * NH))[g];
        float4 i = ((const float4*)(stateI + b * NH))[g];
        can[4 * g + 0] = to2(r.x, i.x);
        can[4 * g + 1] = to2(r.y, i.y);
        can[4 * g + 2] = to2(r.z, i.z);
        can[4 * g + 3] = to2(r.w, i.w);
    }
    __syncthreads();
    v2 x[6];
#pragma unroll
    for (int j = 0; j < 6; ++j) {
        int c = cb + j;
        x[j] = (c >= 0 && c < NH) ? can[c] : to2(0.f, 0.f);
    }
    __syncthreads();   // protect can until all initial reads complete

    float4 Ta[7], Tb[7];
    LOADT(Ta, 0);
    for (int chunk = 0; chunk < 4; ++chunk) {
        for (int k = 0; k < CHUNK; k += 2) {
            int l = chunk * CHUNK + k;
            LOADT(Tb, l + 1);
            stepf(x, Ta);
            {
                int ln = (l + 2 < NSTEPS) ? l + 2 : NSTEPS - 1;
                LOADT(Ta, ln);
            }
            stepf(x, Tb);
        }
        // exchange: owned -> canonical; refresh halo (skip re-read after last)
#pragma unroll
        for (int j = 0; j < 6; ++j) {
            int c = cb + j;
            if (c >= wb && c < wb + 256) can[c] = x[j];
        }
        __syncthreads();
        if (chunk < 3) {
#pragma unroll
            for (int j = 0; j < 6; ++j) {
                int c = cb + j;
                x[j] = (c >= 0 && c < NH) ? can[c] : to2(0.f, 0.f);
            }
            __syncthreads();   // protect can until all reads complete
        }
    }

    // epilogue: phase, + ih, modReLU  (channels 4g..4g+3 from canonical)
    float4 o4 = *(const float4*)(omega + 4 * g);
    float4 m4 = *(const float4*)(mod_bias + 4 * g);
    const float4* ihp = (const float4*)(ws + IH_OFF) + b * 512 + 2 * g;
    float4 ih0 = ihp[0], ih1 = ihp[1];

    float om[4] = { o4.x, o4.y, o4.z, o4.w };
    float mb[4] = { m4.x, m4.y, m4.z, m4.w };
    float ihr[4] = { ih0.x, ih0.z, ih1.x, ih1.z };
    float ihi[4] = { ih0.y, ih0.w, ih1.y, ih1.w };
    float oR[4], oI[4];
#pragma unroll
    for (int j = 0; j < 4; ++j) {
        v2 xx = can[4 * g + j];
        float so, co;
        __sincosf(om[j], &so, &co);
        float zr = ihr[j] + co * xx.x - so * xx.y;
        float zi = ihi[j] + so * xx.x + co * xx.y;
        float mag = sqrtf(zr * zr + zi * zi);
        float sc = fmaxf(mag + mb[j], 0.f) / fmaxf(mag, 1e-8f);
        oR[j] = sc * zr;
        oI[j] = sc * zi;
    }
    *(float4*)(out + b * NH + 4 * g) = make_float4(oR[0], oR[1], oR[2], oR[3]);
    *(float4*)(out + NBATCH * NH + b * NH + 4 * g) = make_float4(oI[0], oI[1], oI[2], oI[3]);
}

// ---------------------------------------------------------------------------
extern "C" void kernel_launch(void* const* d_in, const int* in_sizes, int n_in,
                              void* d_out, int out_size, void* d_ws, size_t ws_size,
                              hipStream_t stream)
{
    const float* inputsR = (const float*)d_in[0];
    const float* inputsI = (const float*)d_in[1];
    const float* stateR  = (const float*)d_in[2];
    const float* stateI  = (const float*)d_in[3];
    const float* weightR = (const float*)d_in[4];
    const float* weightI = (const float*)d_in[5];
    const float* biasR   = (const float*)d_in[6];
    const float* biasI   = (const float*)d_in[7];
    const float* angleA0 = (const float*)d_in[8];
    const float* angleA1 = (const float*)d_in[9];
    const float* angleB0 = (const float*)d_in[10];
    const float* angleB1 = (const float*)d_in[11];
    const float* omega   = (const float*)d_in[12];
    const float* mod_b   = (const float*)d_in[13];
    float* ws = (float*)d_ws;
    float* out = (float*)d_out;

    hipLaunchKernelGGL(prep_kernel, dim3(GEMM_BLOCKS + TRIG_BLOCKS), dim3(256),
                       0, stream, inputsR, inputsI, weightR, weightI,
                       biasR, biasI, angleA0, angleA1, angleB0, angleB1, ws);
    hipLaunchKernelGGL(mesh_kernel, dim3(NBATCH), dim3(256), 0, stream,
                       stateR, stateI, omega, mod_b, ws, out);
}